// Round 6
// baseline (47.033 us; speedup 1.0000x reference)
//
#include <hip/hip_runtime.h>

#define TPB 64   // one wave per block

// One thread = one batch element. ALL three D inputs staged to LDS via
// coalesced float4 loads (packed linear layout). Per-element LDS reads have
// odd dword strides (9/25/49, coprime with 32 banks) -> 2-way aliasing = free.
// c-outer compute keeps the live set ~60 VGPRs so nothing spills or sinks.
__global__ __launch_bounds__(TPB, 4) void cg_main_kernel(
    const float* __restrict__ D1, const float* __restrict__ D2,
    const float* __restrict__ D3, const float* __restrict__ cg,
    float* __restrict__ partials)
{
    __shared__ __align__(16) float s_d1[TPB * 9];    //  2304 B
    __shared__ __align__(16) float s_d2[TPB * 25];   //  6400 B
    __shared__ __align__(16) float s_d3[TPB * 49];   // 12544 B  (21.25 KB total)

    const int lane = threadIdx.x;        // 0..63
    const int blk  = blockIdx.x;         // 4096 blocks

    // ---- coalesced float4 staging (all regions 16B-aligned per block) ----
    {
        const float4* g = (const float4*)(D1 + (size_t)blk * (TPB * 9));   // 144 float4
        float4* s = (float4*)s_d1;
        #pragma unroll
        for (int k = 0; k < 3; ++k) { int i = k * 64 + lane; if (i < 144) s[i] = g[i]; }
    }
    {
        const float4* g = (const float4*)(D2 + (size_t)blk * (TPB * 25));  // 400 float4
        float4* s = (float4*)s_d2;
        #pragma unroll
        for (int k = 0; k < 7; ++k) { int i = k * 64 + lane; if (i < 400) s[i] = g[i]; }
    }
    {
        const float4* g = (const float4*)(D3 + (size_t)blk * (TPB * 49));  // 784 float4
        float4* s = (float4*)s_d3;
        #pragma unroll
        for (int k = 0; k < 13; ++k) { int i = k * 64 + lane; if (i < 784) s[i] = g[i]; }
    }
    __syncthreads();

    // ---- per-element registers (small live set; strides 9/25 conflict-free) ----
    float d1[9];
    #pragma unroll
    for (int i = 0; i < 9; ++i)  d1[i] = s_d1[lane * 9 + i];
    float d2[25];
    #pragma unroll
    for (int j = 0; j < 25; ++j) d2[j] = s_d2[lane * 25 + j];

    float acc = 0.0f;
    #pragma unroll
    for (int c = 0; c < 7; ++c) {
        // D3 column c: lane stride 49 dwords (odd) -> free 2-way
        float d3c[7];
        #pragma unroll
        for (int i = 0; i < 7; ++i) d3c[i] = s_d3[lane * 49 + i * 7 + c];

        #pragma unroll
        for (int a = 0; a < 3; ++a) {
            // U[j] = sum_i d1[a,i] * cg[i,j,c]   (cg wave-uniform -> SGPR operands)
            float U[5];
            #pragma unroll
            for (int j = 0; j < 5; ++j)
                U[j] = fmaf(d1[a * 3 + 2], cg[70 + j * 7 + c],
                       fmaf(d1[a * 3 + 1], cg[35 + j * 7 + c],
                            d1[a * 3 + 0] * cg[      j * 7 + c]));
            #pragma unroll
            for (int b = 0; b < 5; ++b) {
                float L = d2[b * 5] * U[0];
                #pragma unroll
                for (int j = 1; j < 5; ++j) L = fmaf(d2[b * 5 + j], U[j], L);
                float R = cg[(a * 5 + b) * 7] * d3c[0];
                #pragma unroll
                for (int i = 1; i < 7; ++i) R = fmaf(cg[(a * 5 + b) * 7 + i], d3c[i], R);
                const float r = L - R;
                acc = fmaf(r, r, acc);
            }
        }
    }

    // ---- single-wave butterfly reduce ----
    #pragma unroll
    for (int off = 32; off > 0; off >>= 1)
        acc += __shfl_down(acc, off, 64);
    if (lane == 0) partials[blk] = acc;
}

__global__ __launch_bounds__(256) void cg_reduce_kernel(
    const float* __restrict__ partials, float* __restrict__ out,
    int n, float inv)
{
    const int tid = threadIdx.x;
    float s = 0.0f;
    for (int i = tid; i < n; i += 256) s += partials[i];   // deterministic order
    #pragma unroll
    for (int off = 32; off > 0; off >>= 1)
        s += __shfl_down(s, off, 64);
    __shared__ float wsum[4];
    if ((tid & 63) == 0) wsum[tid >> 6] = s;
    __syncthreads();
    if (tid == 0) {
        float t = 0.0f;
        #pragma unroll
        for (int w = 0; w < 4; ++w) t += wsum[w];
        out[0] = t * inv;
    }
}

extern "C" void kernel_launch(void* const* d_in, const int* in_sizes, int n_in,
                              void* d_out, int out_size, void* d_ws, size_t ws_size,
                              hipStream_t stream)
{
    const float* D1 = (const float*)d_in[0];
    const float* D2 = (const float*)d_in[1];
    const float* D3 = (const float*)d_in[2];
    const float* cg = (const float*)d_in[3];
    float* out      = (float*)d_out;
    float* partials = (float*)d_ws;          // 4096 floats = 16 KB scratch

    const int batch   = in_sizes[0] / 9;     // 262144
    const int nblocks = batch / TPB;         // 4096
    const float inv   = 1.0f / ((float)batch * 105.0f);

    cg_main_kernel<<<nblocks, TPB, 0, stream>>>(D1, D2, D3, cg, partials);
    cg_reduce_kernel<<<1, 256, 0, stream>>>(partials, out, nblocks, inv);
}

// Round 7
// 28.411 us; speedup vs baseline: 1.6554x; 1.6554x over previous
//
#include <hip/hip_runtime.h>

#define TPB 256

// TPB=256, 12 waves/CU. One 50KB LDS union buffer used for two staging
// phases (D2 then D3); D3's coalesced float4 loads are issued UP FRONT into
// registers (T14 issue-early/write-late) so their HBM latency hides under
// phase 1. D1 is loaded direct (36B stride, cheap). c-outer compute keeps
// the live set small so nothing spills or gets re-sunk into the loop.
__global__ __launch_bounds__(TPB, 3) void cg_main_kernel(
    const float* __restrict__ D1, const float* __restrict__ D2,
    const float* __restrict__ D3, const float* __restrict__ cg,
    float* __restrict__ partials)
{
    __shared__ __align__(16) float s_buf[TPB * 49];   // 50176 B union buffer
    __shared__ float wsum[TPB / 64];

    const int tid = threadIdx.x;
    const int blk = blockIdx.x;

    // ---- issue ALL global loads up front (coalesced float4) ----
    // order matters for vmcnt: r2 first (needed first), then r3, then d1
    const float4* g2 = (const float4*)(D2 + (size_t)blk * (TPB * 25)); // 1600 f4
    float4 r2[7];
    #pragma unroll
    for (int k = 0; k < 7; ++k) {
        int i = k * TPB + tid;
        r2[k] = (i < 1600) ? g2[i] : make_float4(0.f, 0.f, 0.f, 0.f);
    }
    const float4* g3 = (const float4*)(D3 + (size_t)blk * (TPB * 49)); // 3136 f4
    float4 r3[13];
    #pragma unroll
    for (int k = 0; k < 13; ++k) {
        int i = k * TPB + tid;
        r3[k] = (i < 3136) ? g3[i] : make_float4(0.f, 0.f, 0.f, 0.f);
    }
    float d1[9];
    {
        const float* p1 = D1 + (size_t)(blk * TPB + tid) * 9;
        #pragma unroll
        for (int i = 0; i < 9; ++i) d1[i] = p1[i];
    }

    // ---- phase 1: D2 through LDS (write waits only on r2's vmcnt slice) ----
    float4* sb4 = (float4*)s_buf;
    #pragma unroll
    for (int k = 0; k < 7; ++k) {
        int i = k * TPB + tid;
        if (i < 1600) sb4[i] = r2[k];
    }
    __syncthreads();
    float d2[25];
    #pragma unroll
    for (int j = 0; j < 25; ++j) d2[j] = s_buf[tid * 25 + j];  // stride 25: free 2-way
    __syncthreads();

    // ---- phase 2: D3 through LDS (r3 already landed during phase 1) ----
    #pragma unroll
    for (int k = 0; k < 13; ++k) {
        int i = k * TPB + tid;
        if (i < 3136) sb4[i] = r3[k];
    }
    __syncthreads();

    // ---- c-outer compute: live set ~60 VGPRs ----
    float acc = 0.0f;
    #pragma unroll
    for (int c = 0; c < 7; ++c) {
        float d3c[7];                                   // stride 49: free 2-way
        #pragma unroll
        for (int i = 0; i < 7; ++i) d3c[i] = s_buf[tid * 49 + i * 7 + c];

        #pragma unroll
        for (int a = 0; a < 3; ++a) {
            // U[j] = sum_i d1[a,i] * cg[i,j,c]  (cg wave-uniform -> SGPRs)
            float U[5];
            #pragma unroll
            for (int j = 0; j < 5; ++j)
                U[j] = fmaf(d1[a * 3 + 2], cg[70 + j * 7 + c],
                       fmaf(d1[a * 3 + 1], cg[35 + j * 7 + c],
                            d1[a * 3 + 0] * cg[      j * 7 + c]));
            #pragma unroll
            for (int b = 0; b < 5; ++b) {
                float L = d2[b * 5] * U[0];
                #pragma unroll
                for (int j = 1; j < 5; ++j) L = fmaf(d2[b * 5 + j], U[j], L);
                float R = cg[(a * 5 + b) * 7] * d3c[0];
                #pragma unroll
                for (int i = 1; i < 7; ++i) R = fmaf(cg[(a * 5 + b) * 7 + i], d3c[i], R);
                const float r = L - R;
                acc = fmaf(r, r, acc);
            }
        }
    }

    // ---- block reduce ----
    #pragma unroll
    for (int off = 32; off > 0; off >>= 1)
        acc += __shfl_down(acc, off, 64);
    if ((tid & 63) == 0) wsum[tid >> 6] = acc;
    __syncthreads();
    if (tid == 0) {
        float s = 0.0f;
        #pragma unroll
        for (int w = 0; w < TPB / 64; ++w) s += wsum[w];
        partials[blk] = s;
    }
}

__global__ __launch_bounds__(256) void cg_reduce_kernel(
    const float* __restrict__ partials, float* __restrict__ out,
    int n, float inv)
{
    const int tid = threadIdx.x;
    float s = 0.0f;
    for (int i = tid; i < n; i += 256) s += partials[i];   // deterministic order
    #pragma unroll
    for (int off = 32; off > 0; off >>= 1)
        s += __shfl_down(s, off, 64);
    __shared__ float wsum[4];
    if ((tid & 63) == 0) wsum[tid >> 6] = s;
    __syncthreads();
    if (tid == 0) {
        float t = 0.0f;
        #pragma unroll
        for (int w = 0; w < 4; ++w) t += wsum[w];
        out[0] = t * inv;
    }
}

extern "C" void kernel_launch(void* const* d_in, const int* in_sizes, int n_in,
                              void* d_out, int out_size, void* d_ws, size_t ws_size,
                              hipStream_t stream)
{
    const float* D1 = (const float*)d_in[0];
    const float* D2 = (const float*)d_in[1];
    const float* D3 = (const float*)d_in[2];
    const float* cg = (const float*)d_in[3];
    float* out      = (float*)d_out;
    float* partials = (float*)d_ws;          // 1024 floats = 4 KB scratch

    const int batch   = in_sizes[0] / 9;     // 262144
    const int nblocks = batch / TPB;         // 1024
    const float inv   = 1.0f / ((float)batch * 105.0f);

    cg_main_kernel<<<nblocks, TPB, 0, stream>>>(D1, D2, D3, cg, partials);
    cg_reduce_kernel<<<1, 256, 0, stream>>>(partials, out, nblocks, inv);
}